// Round 10
// baseline (497.571 us; speedup 1.0000x reference)
//
#include <hip/hip_runtime.h>
#include <hip/hip_bf16.h>
#include <cmath>

typedef unsigned short u16;
typedef short short8 __attribute__((ext_vector_type(8)));   // 8 bf16 (4 VGPRs)
typedef float f32x4 __attribute__((ext_vector_type(4)));    // 4 fp32 acc

#define D_ 768
#define NTOK 16384      // B * N = 16 * 1024
#define INNER_ 192
#define HID_ 3072

__device__ __forceinline__ float u2f(u16 u) { return __uint_as_float((unsigned)u << 16); }
__device__ __forceinline__ u16 f2u(float f) {
  __hip_bfloat16 h = __float2bfloat16(f);
  u16 u; __builtin_memcpy(&u, &h, 2); return u;
}
// Flag-aware scalar load/store: harness tensors are f32 (flag=1) or bf16 (0).
__device__ __forceinline__ float ld1(const void* p, size_t i, int f32) {
  return f32 ? ((const float*)p)[i] : u2f(((const u16*)p)[i]);
}
__device__ __forceinline__ void st1(void* p, size_t i, float v, int f32) {
  if (f32) ((float*)p)[i] = v; else ((u16*)p)[i] = f2u(v);
}
__device__ __forceinline__ float gelu_exact(float v) {
  return 0.5f * v * (1.f + erff(v * 0.7071067811865476f));
}
// Unpack 8 bf16 (uint4) -> 8 f32.
__device__ __forceinline__ void unpack8(const uint4 v, float* o) {
  o[0] = u2f((u16)(v.x & 0xffffu)); o[1] = u2f((u16)(v.x >> 16));
  o[2] = u2f((u16)(v.y & 0xffffu)); o[3] = u2f((u16)(v.y >> 16));
  o[4] = u2f((u16)(v.z & 0xffffu)); o[5] = u2f((u16)(v.z >> 16));
  o[6] = u2f((u16)(v.w & 0xffffu)); o[7] = u2f((u16)(v.w >> 16));
}

// ---------------------------------------------------------------------------
// Dtype detector (verified round 4/5): flag 1 = f32 inputs, 0 = bf16 inputs.
// ---------------------------------------------------------------------------
__global__ __launch_bounds__(64) void detect_kernel(const unsigned* __restrict__ x,
                                                    int* __restrict__ flag) {
  int cnt = 0;
  for (int i = threadIdx.x; i < 512; i += 64) {
    const unsigned e0 = (x[i] >> 7) & 0xFFu;
    if (e0 >= 96u && e0 <= 144u) cnt++;
  }
#pragma unroll
  for (int o = 32; o > 0; o >>= 1) cnt += __shfl_down(cnt, o);
  if (threadIdx.x == 0) flag[0] = (cnt < 256) ? 1 : 0;
}

// ---------------------------------------------------------------------------
// Weight conversion to internal bf16 (10 jobs; grid.y = job id).
// ---------------------------------------------------------------------------
struct CvtJob { const void* src; u16* dst; int n4; };  // n4 = elems/4
struct CvtArgs { CvtJob j[10]; };

__global__ __launch_bounds__(256) void cvt_kernel(CvtArgs a, const int* __restrict__ flagp) {
  const int f32 = flagp[0];
  const CvtJob jb = a.j[blockIdx.y];
  const int i = blockIdx.x * 256 + threadIdx.x;
  if (i >= jb.n4) return;
  if (f32) {
    const float4 v = ((const float4*)jb.src)[i];
    const unsigned lo = (unsigned)f2u(v.x) | ((unsigned)f2u(v.y) << 16);
    const unsigned hi = (unsigned)f2u(v.z) | ((unsigned)f2u(v.w) << 16);
    ((uint2*)jb.dst)[i] = make_uint2(lo, hi);
  } else {
    ((uint2*)jb.dst)[i] = ((const uint2*)jb.src)[i];
  }
}

// ---------------------------------------------------------------------------
// Fused LayerNorm: stats + normalize, one block (256 thr) per token.
// ---------------------------------------------------------------------------
__global__ __launch_bounds__(256) void ln_kernel(const void* __restrict__ x,
                                                 const void* __restrict__ w,
                                                 const void* __restrict__ b,
                                                 u16* __restrict__ y,
                                                 const int* __restrict__ flagp) {
  const int fl = flagp[0];
  const size_t t = blockIdx.x;
  float v[3];
  float s = 0.f, s2 = 0.f;
#pragma unroll
  for (int i = 0; i < 3; i++) {
    v[i] = ld1(x, t * D_ + threadIdx.x + 256 * i, fl);
    s += v[i];
    s2 += v[i] * v[i];
  }
#pragma unroll
  for (int o = 32; o > 0; o >>= 1) {
    s += __shfl_down(s, o);
    s2 += __shfl_down(s2, o);
  }
  __shared__ float ps[4], ps2[4];
  __shared__ float smu, srstd;
  const int wid = threadIdx.x >> 6, lane = threadIdx.x & 63;
  if (lane == 0) { ps[wid] = s; ps2[wid] = s2; }
  __syncthreads();
  if (threadIdx.x == 0) {
    const float a = ps[0] + ps[1] + ps[2] + ps[3];
    const float a2 = ps2[0] + ps2[1] + ps2[2] + ps2[3];
    const float mu = a * (1.f / D_);
    smu = mu;
    srstd = rsqrtf(a2 * (1.f / D_) - mu * mu + 1e-5f);
  }
  __syncthreads();
  const float mu = smu, rstd = srstd;
#pragma unroll
  for (int i = 0; i < 3; i++) {
    const int c = threadIdx.x + 256 * i;
    y[t * D_ + c] = f2u((v[i] - mu) * rstd * ld1(w, c, fl) + ld1(b, c, fl));
  }
}

// ---------------------------------------------------------------------------
// MFMA GEMM (m97 structure, 128x128): fv (N=384) and proj (K=192; measured
// better here than on gemmP -- round-8 isolated A/B: 488 vs 494).
// ---------------------------------------------------------------------------
template <int EPI>
__global__ __launch_bounds__(256) void mfma_gemm(const u16* __restrict__ A, int lda,
                                                 const u16* __restrict__ B, int ldb,
                                                 const u16* __restrict__ bias,
                                                 const void* __restrict__ res,
                                                 void* __restrict__ C, int ldc,
                                                 int K, int row0,
                                                 const int* __restrict__ flagp) {
  const int fl = flagp[0];
  __shared__ __align__(16) u16 Asb[128 * 32];
  __shared__ __align__(16) u16 Bsb[128 * 32];
  const int tid = threadIdx.x;
  const int lane = tid & 63;
  const int wv = tid >> 6;
  const int bm = blockIdx.x * 128;
  const int bn = blockIdx.y * 128;
  const int wm = (wv & 1) * 64;
  const int wn = (wv >> 1) * 64;
  const int c0 = tid, c1 = tid + 256;
  const u16* Ag0 = A + (size_t)(bm + (c0 >> 2)) * lda + (c0 & 3) * 8;
  const u16* Ag1 = A + (size_t)(bm + (c1 >> 2)) * lda + (c1 & 3) * 8;
  const u16* Bg0 = B + (size_t)(bn + (c0 >> 2)) * ldb + (c0 & 3) * 8;
  const u16* Bg1 = B + (size_t)(bn + (c1 >> 2)) * ldb + (c1 & 3) * 8;
  u16* la0 = &Asb[c0 * 8];
  u16* la1 = &Asb[c1 * 8];
  u16* lb0 = &Bsb[c0 * 8];
  u16* lb1 = &Bsb[c1 * 8];

  f32x4 acc[4][4];
#pragma unroll
  for (int i = 0; i < 4; i++)
#pragma unroll
    for (int j = 0; j < 4; j++) acc[i][j] = (f32x4){0.f, 0.f, 0.f, 0.f};

  const int ml = lane & 15;
  const int kq = (lane >> 4) * 8;

  for (int k0 = 0; k0 < K; k0 += 32) {
    __syncthreads();
    __builtin_amdgcn_global_load_lds(
        (const __attribute__((address_space(1))) void*)(Ag0 + k0),
        (__attribute__((address_space(3))) void*)la0, 16, 0, 0);
    __builtin_amdgcn_global_load_lds(
        (const __attribute__((address_space(1))) void*)(Ag1 + k0),
        (__attribute__((address_space(3))) void*)la1, 16, 0, 0);
    __builtin_amdgcn_global_load_lds(
        (const __attribute__((address_space(1))) void*)(Bg0 + k0),
        (__attribute__((address_space(3))) void*)lb0, 16, 0, 0);
    __builtin_amdgcn_global_load_lds(
        (const __attribute__((address_space(1))) void*)(Bg1 + k0),
        (__attribute__((address_space(3))) void*)lb1, 16, 0, 0);
    __syncthreads();
    short8 af[4], bf[4];
#pragma unroll
    for (int i = 0; i < 4; i++) {
      af[i] = *(const short8*)&Asb[(wm + i * 16 + ml) * 32 + kq];
      bf[i] = *(const short8*)&Bsb[(wn + i * 16 + ml) * 32 + kq];
    }
#pragma unroll
    for (int i = 0; i < 4; i++)
#pragma unroll
      for (int j = 0; j < 4; j++)
        acc[i][j] = __builtin_amdgcn_mfma_f32_16x16x32_bf16(af[i], bf[j], acc[i][j], 0, 0, 0);
  }

  const int qr = (lane >> 4) * 4;
#pragma unroll
  for (int i = 0; i < 4; i++) {
#pragma unroll
    for (int j = 0; j < 4; j++) {
      const int colg = bn + wn + j * 16 + ml;
      const float bb = u2f(bias[colg]);
#pragma unroll
      for (int r = 0; r < 4; r++) {
        const size_t row = (size_t)row0 + bm + wm + i * 16 + qr + r;
        float v = acc[i][j][r] + bb;
        if (EPI == 1) v = gelu_exact(v);
        if (EPI == 2) {
          v += ld1(res, row * ldc + colg, fl);
          st1(C, row * ldc + colg, v, fl);
        } else {
          ((u16*)C)[row * ldc + colg] = f2u(v);
        }
      }
    }
  }
}

// ---------------------------------------------------------------------------
// mfma_gemmP: 128x256 tile, BK=32, 8 waves, triple-buffered counted-vmcnt
// pipeline. Round-4 measured best for fc1/fc2 (121 us, Occ 35%, 0 conflicts).
// Round-5 (4-wave): regressed. Round-7 (nt stores): regressed (write ampl).
// Plain cached epilogue. Requires M%128==0, N%256==0, K%32==0.
// ---------------------------------------------------------------------------
#define SB8 __builtin_amdgcn_sched_barrier(0)
#define BAR8 __builtin_amdgcn_s_barrier()

template <int EPI>
__global__ __launch_bounds__(512, 4) void mfma_gemmP(const u16* __restrict__ A, int lda,
                                                     const u16* __restrict__ B, int ldb,
                                                     const u16* __restrict__ bias,
                                                     const void* __restrict__ res,
                                                     void* __restrict__ C, int ldc,
                                                     int K, int row0, int gm, int gn,
                                                     const int* __restrict__ flagp) {
  const int fl = flagp[0];
  __shared__ __align__(16) u16 L[3][(128 + 256) * 32];
  const int tid = threadIdx.x;
  const int lane = tid & 63;
  const int wv = tid >> 6;

  int mb_, nb_;
  {
    const int bid = blockIdx.x;
    const int ntot = gm * gn;
    if ((ntot & 511) == 0 && (512 % gm) == 0 && gm >= 2) {
      const int l = bid >> 8, p = bid & 255;
      const int G = gm >> 1;
      nb_ = (l >> 1) * (512 / gm) + p / G;
      mb_ = (p % G) * 2 + (l & 1);
    } else {
      mb_ = bid % gm;
      nb_ = bid / gm;
    }
  }
  const int bm = mb_ * 128;
  const int bn = nb_ * 256;

  const int wm = (wv & 1) * 64;
  const int wn = (wv >> 1) * 64;
  const int ml = lane & 15;
  const int qk = lane >> 4;

  const int srow = tid >> 2;
  const int q_s = (tid & 3) ^ ((srow >> 1) & 3);
  const size_t gaA  = (size_t)(bm + srow) * lda + q_s * 8;
  const size_t gbB0 = (size_t)(bn + srow) * ldb + q_s * 8;
  const size_t gbB1 = (size_t)(bn + srow + 128) * ldb + q_s * 8;

  int offA[4], offB[4];
#pragma unroll
  for (int i = 0; i < 4; i++) {
    const int r = wm + i * 16 + ml;
    offA[i] = (r * 4 + (qk ^ ((r >> 1) & 3))) * 8;
  }
#pragma unroll
  for (int j = 0; j < 4; j++) {
    const int r = wn + j * 16 + ml;
    offB[j] = 4096 + (r * 4 + (qk ^ ((r >> 1) & 3))) * 8;
  }

  f32x4 acc[4][4];
#pragma unroll
  for (int i = 0; i < 4; i++)
#pragma unroll
    for (int j = 0; j < 4; j++) acc[i][j] = (f32x4){0.f, 0.f, 0.f, 0.f};

  const int NT = K >> 5;

#define STGP(tilex) do {                                                            \
    const size_t k_ = (size_t)(tilex) * 32;                                         \
    u16* lb_ = &L[(tilex) % 3][0];                                                  \
    __builtin_amdgcn_global_load_lds(                                               \
        (const __attribute__((address_space(1))) void*)(A + gaA + k_),              \
        (__attribute__((address_space(3))) void*)(lb_ + tid * 8), 16, 0, 0);        \
    __builtin_amdgcn_global_load_lds(                                               \
        (const __attribute__((address_space(1))) void*)(B + gbB0 + k_),             \
        (__attribute__((address_space(3))) void*)(lb_ + 4096 + tid * 8), 16, 0, 0); \
    __builtin_amdgcn_global_load_lds(                                               \
        (const __attribute__((address_space(1))) void*)(B + gbB1 + k_),             \
        (__attribute__((address_space(3))) void*)(lb_ + 4096 + (tid + 512) * 8), 16, 0, 0); \
  } while (0)

  STGP(0);
  if (NT > 1) {
    STGP(1);
    asm volatile("s_waitcnt vmcnt(3)" ::: "memory");
  } else {
    asm volatile("s_waitcnt vmcnt(0)" ::: "memory");
  }
  SB8; BAR8; SB8;

  for (int t = 0; t < NT; t++) {
    const u16* Lb = &L[t % 3][0];
    short8 af[4], bf[4];
#pragma unroll
    for (int j = 0; j < 4; j++) bf[j] = *(const short8*)(Lb + offB[j]);
#pragma unroll
    for (int i = 0; i < 4; i++) af[i] = *(const short8*)(Lb + offA[i]);
    if (t + 2 < NT) {
      STGP(t + 2);
      asm volatile("s_waitcnt vmcnt(3)" ::: "memory");
    } else if (t + 1 < NT) {
      asm volatile("s_waitcnt vmcnt(0)" ::: "memory");
    }
    SB8; BAR8;
    asm volatile("s_waitcnt lgkmcnt(0)" ::: "memory"); SB8;
    __builtin_amdgcn_s_setprio(1);
#pragma unroll
    for (int i = 0; i < 4; i++)
#pragma unroll
      for (int j = 0; j < 4; j++)
        acc[i][j] = __builtin_amdgcn_mfma_f32_16x16x32_bf16(af[i], bf[j], acc[i][j], 0, 0, 0);
    __builtin_amdgcn_s_setprio(0);
    SB8; BAR8;
  }
#undef STGP

  const int qr = (lane >> 4) * 4;
#pragma unroll
  for (int i = 0; i < 4; i++) {
#pragma unroll
    for (int j = 0; j < 4; j++) {
      const int colg = bn + wn + j * 16 + ml;
      const float bb = u2f(bias[colg]);
#pragma unroll
      for (int r = 0; r < 4; r++) {
        const size_t row = (size_t)row0 + bm + wm + i * 16 + qr + r;
        float v = acc[i][j][r] + bb;
        if (EPI == 1) v = gelu_exact(v);
        if (EPI == 2) {
          v += ld1(res, row * ldc + colg, fl);
          st1(C, row * ldc + colg, v, fl);
        } else {
          ((u16*)C)[row * ldc + colg] = f2u(v);
        }
      }
    }
  }
}

// ---------------------------------------------------------------------------
// Cluster pipeline (round-10, bugfixed): 3 kernels, stream-ordered.
// Round-9 bugs fixed: (1) SMs/SMm are per (b,e,token) = 131072 entries (were
// 16384 -> overflow); (2) C2/C3 now 512 threads so all tid<384 sections are
// fully covered (were 256 threads -> centers/outc/outf for m>=10 garbage).
// Per-token/per-center float op ORDER identical to the round-1 kernel; only
// partial-sum combination order differs (2-way global atomics).
// ---------------------------------------------------------------------------

// C1: one 64-thread block per (be, m): pool f/v centers (exact dw/dh order),
// rcn, and zero OUTC/CNT.
__global__ __launch_bounds__(64) void cluster_centers(const u16* __restrict__ FV,
                                                      float* __restrict__ CEN,
                                                      float* __restrict__ VCEN,
                                                      float* __restrict__ RCN,
                                                      float* __restrict__ OUTC,
                                                      int* __restrict__ CNT) {
  const int be = blockIdx.x >> 4, m = blockIdx.x & 15;
  const int b = be >> 3, e = be & 7;
  const int lane = threadIdx.x;
  const int pw = m >> 2, ph = m & 3;
  __shared__ float cnL[24];

  const int isF = (lane < 24);
  const int isV = (lane >= 32 && lane < 56);
  const int ch = isF ? lane : (lane - 32);
  const u16* base = FV + ((size_t)b * 1024) * 384 + e * 24 + (isV ? 192 : 0);

  if (isF || isV) {
    float sum = 0.f;
    for (int dw = 0; dw < 8; dw++) {
      const int nb0 = (pw * 8 + dw) * 32 + ph * 8;   // n = w*32 + h
#pragma unroll
      for (int dh = 0; dh < 8; dh++)
        sum += u2f(base[(size_t)(nb0 + dh) * 384 + ch]);
    }
    const float c = sum * (1.f / 64.f);
    const int idx = (be * 16 + m) * 24 + ch;
    if (isF) { CEN[idx] = c; cnL[ch] = c; OUTC[idx] = 0.f; }
    else     { VCEN[idx] = c; }
  }
  if (lane == 56) CNT[be * 16 + m] = 0;
  __syncthreads();
  if (lane == 0) {
    float s = 0.f;
    for (int c2 = 0; c2 < 24; c2++) { const float v = cnL[c2]; s += v * v; }
    RCN[be * 16 + m] = 1.f / fmaxf(sqrtf(s), 1e-12f);
  }
}

// C2: 2 blocks per (b,e), 512 tokens each, 512 threads. Per-token argmax
// (identical op order), deterministic per-block chunked scan of s*v into
// partial outc, one global atomicAdd per (m,ch) per block.
__global__ __launch_bounds__(512) void cluster_assign(const u16* __restrict__ FV,
                                                      const float* __restrict__ CEN,
                                                      const float* __restrict__ RCN,
                                                      float* __restrict__ OUTC,
                                                      int* __restrict__ CNT,
                                                      float* __restrict__ SMs,
                                                      int* __restrict__ SMm,
                                                      const void* __restrict__ alpha_p,
                                                      const void* __restrict__ beta_p,
                                                      const int* __restrict__ flagp) {
  const int fl = flagp[0];
  const int be = blockIdx.x >> 1, half = blockIdx.x & 1;
  const int b = be >> 3, e = be & 7;
  const int tid = threadIdx.x;
  const float alpha = ld1(alpha_p, 0, fl), beta = ld1(beta_p, 0, fl);

  __shared__ __align__(16) u16 SF[512 * 24];   // F rows of this half (24 KB)
  __shared__ __align__(16) u16 SV[512 * 24];   // V rows of this half (24 KB)
  __shared__ float cnr[16][24];
  __shared__ float rcnL[16];
  __shared__ float sms[512];
  __shared__ int smm[512];
  __shared__ int cntp[16];

  const int n0 = half * 512;                   // local token base
  const u16* Fg = FV + ((size_t)b * 1024 + n0) * 384 + e * 24;
  const u16* Vg = Fg + 192;

  // Stage F and V rows (3 uint4 per thread each), load centers.
  for (int c = tid; c < 1536; c += 512) {
    const int n = c / 3, q = c - n * 3;
    *(uint4*)&SF[n * 24 + q * 8] = *(const uint4*)(Fg + (size_t)n * 384 + q * 8);
    *(uint4*)&SV[n * 24 + q * 8] = *(const uint4*)(Vg + (size_t)n * 384 + q * 8);
  }
  if (tid < 384) {
    const int m = tid / 24, ch = tid - m * 24;
    cnr[m][ch] = CEN[(be * 16 + m) * 24 + ch];
  }
  if (tid < 16) { rcnL[tid] = RCN[be * 16 + tid]; cntp[tid] = 0; }
  __syncthreads();

  // Per-token argmax (op order identical to round-1 kernel).
  {
    float xf[24];
    const uint4* ra = (const uint4*)&SF[tid * 24];
#pragma unroll
    for (int q = 0; q < 3; q++) unpack8(ra[q], &xf[q * 8]);
    float ss = 0.f;
#pragma unroll
    for (int ch = 0; ch < 24; ch++) ss = fmaf(xf[ch], xf[ch], ss);
    const float rn = 1.f / fmaxf(sqrtf(ss), 1e-12f);
    float best = -3.4e38f;
    int bm_ = 0;
    for (int m = 0; m < 16; m++) {
      float d = 0.f;
#pragma unroll
      for (int k = 0; k < 12; k++) {
        const float2 c = *(const float2*)&cnr[m][2 * k];
        d = fmaf(c.x, xf[2 * k], d); d = fmaf(c.y, xf[2 * k + 1], d);
      }
      d *= rn * rcnL[m];
      const float dd = sqrtf(fmaxf(2.f - 2.f * d, 1e-12f));
      const float z = beta + alpha * expf(-dd);
      const float sim = (z >= 0.f) ? z : 0.2f * z;
      if (sim > best) { best = sim; bm_ = m; }
    }
    smm[tid] = bm_;
    sms[tid] = best;
    atomicAdd(&cntp[bm_], 1);
    SMm[(size_t)be * 1024 + n0 + tid] = bm_;
    SMs[(size_t)be * 1024 + n0 + tid] = best;
  }
  __syncthreads();

  // Deterministic chunked scan: 384 (m,ch) tasks over 512 tokens from LDS.
  if (tid < 384) {
    const int m = tid / 24, ch = tid - m * 24;
    float acc = 0.f;
    for (int n = 0; n < 512; n++) {
      if (smm[n] == m) acc = fmaf(sms[n], u2f(SV[n * 24 + ch]), acc);
    }
    atomicAdd(&OUTC[(be * 16 + m) * 24 + ch], acc);
  }
  if (tid < 16) atomicAdd(&CNT[be * 16 + tid], cntp[tid]);
}

// C3: finalize centers and broadcast to tokens (write to FV f-cols).
__global__ __launch_bounds__(512) void cluster_bcast(u16* __restrict__ FV,
                                                     const float* __restrict__ OUTC,
                                                     const float* __restrict__ VCEN,
                                                     const int* __restrict__ CNT,
                                                     const float* __restrict__ SMs,
                                                     const int* __restrict__ SMm) {
  const int be = blockIdx.x >> 1, half = blockIdx.x & 1;
  const int b = be >> 3, e = be & 7;
  const int tid = threadIdx.x;
  __shared__ float outf[16][24];

  if (tid < 384) {
    const int m = tid / 24, ch = tid - m * 24;
    outf[m][ch] = (OUTC[(be * 16 + m) * 24 + ch] + VCEN[(be * 16 + m) * 24 + ch]) /
                  ((float)CNT[be * 16 + m] + 1.f);
  }
  __syncthreads();

  const int n0 = half * 512;
  const int m = SMm[(size_t)be * 1024 + n0 + tid];
  const float s = SMs[(size_t)be * 1024 + n0 + tid];
  unsigned w[12];
#pragma unroll
  for (int k = 0; k < 12; k++) {
    w[k] = (unsigned)f2u(s * outf[m][2 * k]) |
           ((unsigned)f2u(s * outf[m][2 * k + 1]) << 16);
  }
  uint4* dst = (uint4*)(FV + ((size_t)b * 1024 + n0 + tid) * 384 + e * 24);
  dst[0] = make_uint4(w[0], w[1], w[2], w[3]);
  dst[1] = make_uint4(w[4], w[5], w[6], w[7]);
  dst[2] = make_uint4(w[8], w[9], w[10], w[11]);
}

// ---------------------------------------------------------------------------
// Workspace layout (floor ~49.7 MB; G beyond that, adaptive):
//   flag @0 | fv_w @256 | proj_w @590080 | fc1_w @884992 | fc2_w @5603584
//   fvb @10322176 | projb @10322944 | fc1b @10324480 | fc2b @10330624
//   Y1 bf16 16384x768 @10332416 | FV bf16 16384x384 @35498240
//   CEN @48081152 | VCEN @48277760 | RCN @48474368 | OUTC @48482560
//   CNT @48679168 | SMs[131072] @48687360 | SMm[131072] @49211648
//   G @49735936
// ---------------------------------------------------------------------------
extern "C" void kernel_launch(void* const* d_in, const int* in_sizes, int n_in,
                              void* d_out, int out_size, void* d_ws, size_t ws_size,
                              hipStream_t stream) {
  const void* x      = d_in[0];
  const void* ln1_w  = d_in[1];
  const void* ln1_b  = d_in[2];
  const void* f_w    = d_in[3];
  const void* f_b    = d_in[4];
  const void* v_w    = d_in[5];
  const void* v_b    = d_in[6];
  const void* proj_w = d_in[7];
  const void* proj_b = d_in[8];
  const void* alpha  = d_in[9];
  const void* beta   = d_in[10];
  const void* ln2_w  = d_in[11];
  const void* ln2_b  = d_in[12];
  const void* fc1_w  = d_in[13];
  const void* fc1_b  = d_in[14];
  const void* fc2_w  = d_in[15];
  const void* fc2_b  = d_in[16];

  char* ws = (char*)d_ws;
  int* flag  = (int*)(ws + 0);
  u16* fvw   = (u16*)(ws + 256);
  u16* prw   = (u16*)(ws + 590080);
  u16* f1w   = (u16*)(ws + 884992);
  u16* f2w   = (u16*)(ws + 5603584);
  u16* fvb   = (u16*)(ws + 10322176);
  u16* prb   = (u16*)(ws + 10322944);
  u16* f1b   = (u16*)(ws + 10324480);
  u16* f2b_  = (u16*)(ws + 10330624);
  u16* Y1    = (u16*)(ws + 10332416);
  u16* FV    = (u16*)(ws + 35498240);
  float* CEN  = (float*)(ws + 48081152);
  float* VCEN = (float*)(ws + 48277760);
  float* RCN  = (float*)(ws + 48474368);
  float* OUTC = (float*)(ws + 48482560);
  int*   CNT  = (int*)  (ws + 48679168);
  float* SMs  = (float*)(ws + 48687360);
  int*   SMm  = (int*)  (ws + 49211648);
  u16* Gext  = (u16*)(ws + 49735936);

  // fc1/fc2 chunk rows (multiple of 256), pure function of ws_size.
  const long extra = (long)ws_size - 49735936L;
  u16* G; long crows;
  if (extra >= (long)NTOK * HID_ * 2) { G = Gext; crows = NTOK; }
  else if (extra >= 256L * HID_ * 2) { G = Gext; crows = (extra / (HID_ * 2)) / 256 * 256; }
  else { G = FV; crows = 2048; }  // FV dead after proj; 2048*3072*2 = 12.58 MB fits

  detect_kernel<<<1, 64, 0, stream>>>((const unsigned*)x, flag);

  CvtArgs ca;
  ca.j[0] = {f_w,    fvw,            147456 / 4};
  ca.j[1] = {v_w,    fvw + 147456,   147456 / 4};
  ca.j[2] = {proj_w, prw,            147456 / 4};
  ca.j[3] = {fc1_w,  f1w,            2359296 / 4};
  ca.j[4] = {fc2_w,  f2w,            2359296 / 4};
  ca.j[5] = {f_b,    fvb,            192 / 4};
  ca.j[6] = {v_b,    fvb + 192,      192 / 4};
  ca.j[7] = {proj_b, prb,            768 / 4};
  ca.j[8] = {fc1_b,  f1b,            3072 / 4};
  ca.j[9] = {fc2_b,  f2b_,           768 / 4};
  cvt_kernel<<<dim3(2304, 10), 256, 0, stream>>>(ca, flag);

  // ln1(x) -> Y1 (bf16)
  ln_kernel<<<NTOK, 256, 0, stream>>>(x, ln1_w, ln1_b, Y1, flag);
  // FV = Y1 * [f_w; v_w]^T + [f_b; v_b]   (M=16384, N=384, K=768)
  mfma_gemm<0><<<dim3(128, 3), 256, 0, stream>>>(
      Y1, D_, fvw, D_, fvb, nullptr, FV, 384, D_, 0, flag);
  // Cluster pipeline (3 stages, stream-ordered).
  cluster_centers<<<2048, 64, 0, stream>>>(FV, CEN, VCEN, RCN, OUTC, CNT);
  cluster_assign<<<256, 512, 0, stream>>>(FV, CEN, RCN, OUTC, CNT, SMs, SMm,
                                          alpha, beta, flag);
  cluster_bcast<<<256, 512, 0, stream>>>(FV, OUTC, VCEN, CNT, SMs, SMm);
  // h = CL * proj_w^T + proj_b + x -> d_out (flag dtype). A = FV cols [0,192).
  mfma_gemm<2><<<dim3(128, 6), 256, 0, stream>>>(
      FV, 384, prw, INNER_, prb, x, d_out, D_, INNER_, 0, flag);
  // ln2(h) -> Y1 (bf16)
  ln_kernel<<<NTOK, 256, 0, stream>>>(d_out, ln2_w, ln2_b, Y1, flag);
  // fc1 -> G (gelu), fc2 + h residual -> d_out in place, chunked (128x256)
  for (long t0 = 0; t0 < NTOK; t0 += crows) {
    const long ct = (t0 + crows <= NTOK) ? crows : (NTOK - t0);
    const int gm1 = (int)(ct / 128), gn1 = HID_ / 256;
    const int gm2 = (int)(ct / 128), gn2 = D_ / 256;
    mfma_gemmP<1><<<dim3(gm1 * gn1), 512, 0, stream>>>(
        Y1 + t0 * D_, D_, f1w, D_, f1b, nullptr, G, HID_, D_, 0, gm1, gn1, flag);
    mfma_gemmP<2><<<dim3(gm2 * gn2), 512, 0, stream>>>(
        G, HID_, f2w, HID_, f2b_, d_out, d_out, D_, HID_, (int)t0, gm2, gn2, flag);
  }
}

// Round 11
// 480.143 us; speedup vs baseline: 1.0363x; 1.0363x over previous
//
#include <hip/hip_runtime.h>
#include <hip/hip_bf16.h>
#include <cmath>

typedef unsigned short u16;
typedef short short8 __attribute__((ext_vector_type(8)));   // 8 bf16 (4 VGPRs)
typedef float f32x4 __attribute__((ext_vector_type(4)));    // 4 fp32 acc

#define D_ 768
#define NTOK 16384      // B * N = 16 * 1024
#define INNER_ 192
#define HID_ 3072

__device__ __forceinline__ float u2f(u16 u) { return __uint_as_float((unsigned)u << 16); }
__device__ __forceinline__ u16 f2u(float f) {
  __hip_bfloat16 h = __float2bfloat16(f);
  u16 u; __builtin_memcpy(&u, &h, 2); return u;
}
// Flag-aware scalar load/store: harness tensors are f32 (flag=1) or bf16 (0).
__device__ __forceinline__ float ld1(const void* p, size_t i, int f32) {
  return f32 ? ((const float*)p)[i] : u2f(((const u16*)p)[i]);
}
__device__ __forceinline__ void st1(void* p, size_t i, float v, int f32) {
  if (f32) ((float*)p)[i] = v; else ((u16*)p)[i] = f2u(v);
}
__device__ __forceinline__ float gelu_exact(float v) {
  return 0.5f * v * (1.f + erff(v * 0.7071067811865476f));
}
// Unpack 8 bf16 (uint4) -> 8 f32.
__device__ __forceinline__ void unpack8(const uint4 v, float* o) {
  o[0] = u2f((u16)(v.x & 0xffffu)); o[1] = u2f((u16)(v.x >> 16));
  o[2] = u2f((u16)(v.y & 0xffffu)); o[3] = u2f((u16)(v.y >> 16));
  o[4] = u2f((u16)(v.z & 0xffffu)); o[5] = u2f((u16)(v.z >> 16));
  o[6] = u2f((u16)(v.w & 0xffffu)); o[7] = u2f((u16)(v.w >> 16));
}

// ---------------------------------------------------------------------------
// Dtype detector (verified round 4/5): flag 1 = f32 inputs, 0 = bf16 inputs.
// ---------------------------------------------------------------------------
__global__ __launch_bounds__(64) void detect_kernel(const unsigned* __restrict__ x,
                                                    int* __restrict__ flag) {
  int cnt = 0;
  for (int i = threadIdx.x; i < 512; i += 64) {
    const unsigned e0 = (x[i] >> 7) & 0xFFu;
    if (e0 >= 96u && e0 <= 144u) cnt++;
  }
#pragma unroll
  for (int o = 32; o > 0; o >>= 1) cnt += __shfl_down(cnt, o);
  if (threadIdx.x == 0) flag[0] = (cnt < 256) ? 1 : 0;
}

// ---------------------------------------------------------------------------
// Weight conversion to internal bf16 (10 jobs; grid.y = job id).
// ---------------------------------------------------------------------------
struct CvtJob { const void* src; u16* dst; int n4; };  // n4 = elems/4
struct CvtArgs { CvtJob j[10]; };

__global__ __launch_bounds__(256) void cvt_kernel(CvtArgs a, const int* __restrict__ flagp) {
  const int f32 = flagp[0];
  const CvtJob jb = a.j[blockIdx.y];
  const int i = blockIdx.x * 256 + threadIdx.x;
  if (i >= jb.n4) return;
  if (f32) {
    const float4 v = ((const float4*)jb.src)[i];
    const unsigned lo = (unsigned)f2u(v.x) | ((unsigned)f2u(v.y) << 16);
    const unsigned hi = (unsigned)f2u(v.z) | ((unsigned)f2u(v.w) << 16);
    ((uint2*)jb.dst)[i] = make_uint2(lo, hi);
  } else {
    ((uint2*)jb.dst)[i] = ((const uint2*)jb.src)[i];
  }
}

// ---------------------------------------------------------------------------
// Fused LayerNorm: stats + normalize, one block (256 thr) per token.
// ---------------------------------------------------------------------------
__global__ __launch_bounds__(256) void ln_kernel(const void* __restrict__ x,
                                                 const void* __restrict__ w,
                                                 const void* __restrict__ b,
                                                 u16* __restrict__ y,
                                                 const int* __restrict__ flagp) {
  const int fl = flagp[0];
  const size_t t = blockIdx.x;
  float v[3];
  float s = 0.f, s2 = 0.f;
#pragma unroll
  for (int i = 0; i < 3; i++) {
    v[i] = ld1(x, t * D_ + threadIdx.x + 256 * i, fl);
    s += v[i];
    s2 += v[i] * v[i];
  }
#pragma unroll
  for (int o = 32; o > 0; o >>= 1) {
    s += __shfl_down(s, o);
    s2 += __shfl_down(s2, o);
  }
  __shared__ float ps[4], ps2[4];
  __shared__ float smu, srstd;
  const int wid = threadIdx.x >> 6, lane = threadIdx.x & 63;
  if (lane == 0) { ps[wid] = s; ps2[wid] = s2; }
  __syncthreads();
  if (threadIdx.x == 0) {
    const float a = ps[0] + ps[1] + ps[2] + ps[3];
    const float a2 = ps2[0] + ps2[1] + ps2[2] + ps2[3];
    const float mu = a * (1.f / D_);
    smu = mu;
    srstd = rsqrtf(a2 * (1.f / D_) - mu * mu + 1e-5f);
  }
  __syncthreads();
  const float mu = smu, rstd = srstd;
#pragma unroll
  for (int i = 0; i < 3; i++) {
    const int c = threadIdx.x + 256 * i;
    y[t * D_ + c] = f2u((v[i] - mu) * rstd * ld1(w, c, fl) + ld1(b, c, fl));
  }
}

// ---------------------------------------------------------------------------
// mfma_gemmS: 128x128 tile, 4 waves (wave = 64x64), gemmP-style pipeline:
// TRIPLE-buffered LDS (3 x 16 KB = 48 KB -> 3 blocks/CU), counted vmcnt(4)
// (never 0 in-loop), XOR swizzle both-sides (0 bank conflicts; the old
// m97-structure kernel had 9.4M/dispatch), setprio around MFMA, one
// barrier-pair per K-tile. Round-11: replaces the old 2-barrier 128^2 kernel
// for fv (N=384) and proj (K=192) -- the pipeline that took fc1 145->121 us,
// at the tile that fits these shapes. Requires M%128==0, N%128==0, K%32==0.
// K accumulation order linear (bit-identical to all prior kernels).
// ---------------------------------------------------------------------------
#define SB8 __builtin_amdgcn_sched_barrier(0)
#define BAR8 __builtin_amdgcn_s_barrier()

template <int EPI>
__global__ __launch_bounds__(256, 3) void mfma_gemmS(const u16* __restrict__ A, int lda,
                                                     const u16* __restrict__ B, int ldb,
                                                     const u16* __restrict__ bias,
                                                     const void* __restrict__ res,
                                                     void* __restrict__ C, int ldc,
                                                     int K, int row0,
                                                     const int* __restrict__ flagp) {
  const int fl = flagp[0];
  __shared__ __align__(16) u16 L[3][128 * 32 * 2];   // A @0 (4096 el), B @4096
  const int tid = threadIdx.x;
  const int lane = tid & 63;
  const int wv = tid >> 6;
  const int bm = blockIdx.x * 128;
  const int bn = blockIdx.y * 128;
  const int wm = (wv & 1) * 64;
  const int wn = (wv >> 1) * 64;
  const int ml = lane & 15;
  const int qk = lane >> 4;        // 16B chunk within k-slice

  // Staging: thread covers chunks c0 = tid (row = tid>>2, slot = tid&3) and
  // c1 = tid+256 (row+64, same slot). Global chunk q = slot ^ ((row>>1)&3)
  // ((row>>1)&3 invariant under row+64). LDS dest linear at c*8.
  const int srow = tid >> 2;
  const int q_s = (tid & 3) ^ ((srow >> 1) & 3);
  const size_t gA0 = (size_t)(bm + srow) * lda + q_s * 8;
  const size_t gA1 = (size_t)(bm + srow + 64) * lda + q_s * 8;
  const size_t gB0 = (size_t)(bn + srow) * ldb + q_s * 8;
  const size_t gB1 = (size_t)(bn + srow + 64) * ldb + q_s * 8;

  // LDS read offsets (elems), swizzled: logical chunk qk of row r lives at
  // slot qk ^ ((r>>1)&3).
  int offA[4], offB[4];
#pragma unroll
  for (int i = 0; i < 4; i++) {
    const int rA = wm + i * 16 + ml;
    offA[i] = (rA * 4 + (qk ^ ((rA >> 1) & 3))) * 8;
    const int rB = wn + i * 16 + ml;
    offB[i] = 4096 + (rB * 4 + (qk ^ ((rB >> 1) & 3))) * 8;
  }

  f32x4 acc[4][4];
#pragma unroll
  for (int i = 0; i < 4; i++)
#pragma unroll
    for (int j = 0; j < 4; j++) acc[i][j] = (f32x4){0.f, 0.f, 0.f, 0.f};

  const int NT = K >> 5;

#define STGS(tilex) do {                                                            \
    const size_t k_ = (size_t)(tilex) * 32;                                         \
    u16* lb_ = &L[(tilex) % 3][0];                                                  \
    __builtin_amdgcn_global_load_lds(                                               \
        (const __attribute__((address_space(1))) void*)(A + gA0 + k_),              \
        (__attribute__((address_space(3))) void*)(lb_ + tid * 8), 16, 0, 0);        \
    __builtin_amdgcn_global_load_lds(                                               \
        (const __attribute__((address_space(1))) void*)(A + gA1 + k_),              \
        (__attribute__((address_space(3))) void*)(lb_ + (tid + 256) * 8), 16, 0, 0);\
    __builtin_amdgcn_global_load_lds(                                               \
        (const __attribute__((address_space(1))) void*)(B + gB0 + k_),              \
        (__attribute__((address_space(3))) void*)(lb_ + 4096 + tid * 8), 16, 0, 0); \
    __builtin_amdgcn_global_load_lds(                                               \
        (const __attribute__((address_space(1))) void*)(B + gB1 + k_),              \
        (__attribute__((address_space(3))) void*)(lb_ + 4096 + (tid + 256) * 8), 16, 0, 0); \
  } while (0)

  // Prologue
  STGS(0);
  if (NT > 1) {
    STGS(1);
    asm volatile("s_waitcnt vmcnt(4)" ::: "memory");   // tile 0 landed
  } else {
    asm volatile("s_waitcnt vmcnt(0)" ::: "memory");
  }
  SB8; BAR8; SB8;

  for (int t = 0; t < NT; t++) {
    const u16* Lb = &L[t % 3][0];
    short8 af[4], bf[4];
#pragma unroll
    for (int j = 0; j < 4; j++) bf[j] = *(const short8*)(Lb + offB[j]);
#pragma unroll
    for (int i = 0; i < 4; i++) af[i] = *(const short8*)(Lb + offA[i]);
    if (t + 2 < NT) {
      STGS(t + 2);
      asm volatile("s_waitcnt vmcnt(4)" ::: "memory"); // tile t+1 landed
    } else if (t + 1 < NT) {
      asm volatile("s_waitcnt vmcnt(0)" ::: "memory"); // drain last tile
    }
    SB8; BAR8;
    asm volatile("s_waitcnt lgkmcnt(0)" ::: "memory"); SB8;
    __builtin_amdgcn_s_setprio(1);
#pragma unroll
    for (int i = 0; i < 4; i++)
#pragma unroll
      for (int j = 0; j < 4; j++)
        acc[i][j] = __builtin_amdgcn_mfma_f32_16x16x32_bf16(af[i], bf[j], acc[i][j], 0, 0, 0);
    __builtin_amdgcn_s_setprio(0);
    SB8; BAR8;
  }
#undef STGS

  // Epilogue. C/D layout: col = lane&15, row = (lane>>4)*4 + reg.
  const int qr = (lane >> 4) * 4;
#pragma unroll
  for (int i = 0; i < 4; i++) {
#pragma unroll
    for (int j = 0; j < 4; j++) {
      const int colg = bn + wn + j * 16 + ml;
      const float bb = u2f(bias[colg]);
#pragma unroll
      for (int r = 0; r < 4; r++) {
        const size_t row = (size_t)row0 + bm + wm + i * 16 + qr + r;
        float v = acc[i][j][r] + bb;
        if (EPI == 1) v = gelu_exact(v);
        if (EPI == 2) {
          v += ld1(res, row * ldc + colg, fl);
          st1(C, row * ldc + colg, v, fl);
        } else {
          ((u16*)C)[row * ldc + colg] = f2u(v);
        }
      }
    }
  }
}

// ---------------------------------------------------------------------------
// mfma_gemmP: 128x256 tile, BK=32, 8 waves, triple-buffered counted-vmcnt
// pipeline. Round-4 measured best for fc1/fc2 (121 us, Occ 35%, 0 conflicts).
// Round-5 (4-wave): regressed. Round-7 (nt stores): regressed (write ampl).
// Plain cached epilogue. Requires M%128==0, N%256==0, K%32==0.
// ---------------------------------------------------------------------------
template <int EPI>
__global__ __launch_bounds__(512, 4) void mfma_gemmP(const u16* __restrict__ A, int lda,
                                                     const u16* __restrict__ B, int ldb,
                                                     const u16* __restrict__ bias,
                                                     const void* __restrict__ res,
                                                     void* __restrict__ C, int ldc,
                                                     int K, int row0, int gm, int gn,
                                                     const int* __restrict__ flagp) {
  const int fl = flagp[0];
  __shared__ __align__(16) u16 L[3][(128 + 256) * 32];
  const int tid = threadIdx.x;
  const int lane = tid & 63;
  const int wv = tid >> 6;

  int mb_, nb_;
  {
    const int bid = blockIdx.x;
    const int ntot = gm * gn;
    if ((ntot & 511) == 0 && (512 % gm) == 0 && gm >= 2) {
      const int l = bid >> 8, p = bid & 255;
      const int G = gm >> 1;
      nb_ = (l >> 1) * (512 / gm) + p / G;
      mb_ = (p % G) * 2 + (l & 1);
    } else {
      mb_ = bid % gm;
      nb_ = bid / gm;
    }
  }
  const int bm = mb_ * 128;
  const int bn = nb_ * 256;

  const int wm = (wv & 1) * 64;
  const int wn = (wv >> 1) * 64;
  const int ml = lane & 15;
  const int qk = lane >> 4;

  const int srow = tid >> 2;
  const int q_s = (tid & 3) ^ ((srow >> 1) & 3);
  const size_t gaA  = (size_t)(bm + srow) * lda + q_s * 8;
  const size_t gbB0 = (size_t)(bn + srow) * ldb + q_s * 8;
  const size_t gbB1 = (size_t)(bn + srow + 128) * ldb + q_s * 8;

  int offA[4], offB[4];
#pragma unroll
  for (int i = 0; i < 4; i++) {
    const int r = wm + i * 16 + ml;
    offA[i] = (r * 4 + (qk ^ ((r >> 1) & 3))) * 8;
  }
#pragma unroll
  for (int j = 0; j < 4; j++) {
    const int r = wn + j * 16 + ml;
    offB[j] = 4096 + (r * 4 + (qk ^ ((r >> 1) & 3))) * 8;
  }

  f32x4 acc[4][4];
#pragma unroll
  for (int i = 0; i < 4; i++)
#pragma unroll
    for (int j = 0; j < 4; j++) acc[i][j] = (f32x4){0.f, 0.f, 0.f, 0.f};

  const int NT = K >> 5;

#define STGP(tilex) do {                                                            \
    const size_t k_ = (size_t)(tilex) * 32;                                         \
    u16* lb_ = &L[(tilex) % 3][0];                                                  \
    __builtin_amdgcn_global_load_lds(                                               \
        (const __attribute__((address_space(1))) void*)(A + gaA + k_),              \
        (__attribute__((address_space(3))) void*)(lb_ + tid * 8), 16, 0, 0);        \
    __builtin_amdgcn_global_load_lds(                                               \
        (const __attribute__((address_space(1))) void*)(B + gbB0 + k_),             \
        (__attribute__((address_space(3))) void*)(lb_ + 4096 + tid * 8), 16, 0, 0); \
    __builtin_amdgcn_global_load_lds(                                               \
        (const __attribute__((address_space(1))) void*)(B + gbB1 + k_),             \
        (__attribute__((address_space(3))) void*)(lb_ + 4096 + (tid + 512) * 8), 16, 0, 0); \
  } while (0)

  STGP(0);
  if (NT > 1) {
    STGP(1);
    asm volatile("s_waitcnt vmcnt(3)" ::: "memory");
  } else {
    asm volatile("s_waitcnt vmcnt(0)" ::: "memory");
  }
  SB8; BAR8; SB8;

  for (int t = 0; t < NT; t++) {
    const u16* Lb = &L[t % 3][0];
    short8 af[4], bf[4];
#pragma unroll
    for (int j = 0; j < 4; j++) bf[j] = *(const short8*)(Lb + offB[j]);
#pragma unroll
    for (int i = 0; i < 4; i++) af[i] = *(const short8*)(Lb + offA[i]);
    if (t + 2 < NT) {
      STGP(t + 2);
      asm volatile("s_waitcnt vmcnt(3)" ::: "memory");
    } else if (t + 1 < NT) {
      asm volatile("s_waitcnt vmcnt(0)" ::: "memory");
    }
    SB8; BAR8;
    asm volatile("s_waitcnt lgkmcnt(0)" ::: "memory"); SB8;
    __builtin_amdgcn_s_setprio(1);
#pragma unroll
    for (int i = 0; i < 4; i++)
#pragma unroll
      for (int j = 0; j < 4; j++)
        acc[i][j] = __builtin_amdgcn_mfma_f32_16x16x32_bf16(af[i], bf[j], acc[i][j], 0, 0, 0);
    __builtin_amdgcn_s_setprio(0);
    SB8; BAR8;
  }
#undef STGP

  const int qr = (lane >> 4) * 4;
#pragma unroll
  for (int i = 0; i < 4; i++) {
#pragma unroll
    for (int j = 0; j < 4; j++) {
      const int colg = bn + wn + j * 16 + ml;
      const float bb = u2f(bias[colg]);
#pragma unroll
      for (int r = 0; r < 4; r++) {
        const size_t row = (size_t)row0 + bm + wm + i * 16 + qr + r;
        float v = acc[i][j][r] + bb;
        if (EPI == 1) v = gelu_exact(v);
        if (EPI == 2) {
          v += ld1(res, row * ldc + colg, fl);
          st1(C, row * ldc + colg, v, fl);
        } else {
          ((u16*)C)[row * ldc + colg] = f2u(v);
        }
      }
    }
  }
}

// ---------------------------------------------------------------------------
// Cluster kernel (round-1 structure; the round-4 measured-best configuration.
// Round-10's 3-kernel split measured neutral-to-worse -- reverted).
// ---------------------------------------------------------------------------
__global__ __launch_bounds__(512) void cluster_kernel(u16* __restrict__ FV,
                                                      const void* __restrict__ alpha_p,
                                                      const void* __restrict__ beta_p,
                                                      const int* __restrict__ flagp) {
  const int fl = flagp[0];
  const int be = blockIdx.x;       // 0..127
  const int b = be >> 3, e = be & 7;
  const int tid = threadIdx.x;
  const float alpha = ld1(alpha_p, 0, fl), beta = ld1(beta_p, 0, fl);

  __shared__ __align__(16) u16 S[1024 * 24];   // staged F, then V (48 KB)
  __shared__ float cn[16][24];
  __shared__ float vcen[16][24];
  __shared__ float outc[16][24];
  __shared__ float rcn[16];
  __shared__ int cnt[16];

  u16* Fg = FV + ((size_t)b * 1024) * 384 + e * 24;
  const u16* Vg = Fg + 192;

  for (int c = tid; c < 3072; c += 512) {
    const int n = c / 3, q = c - n * 3;
    *(uint4*)&S[n * 24 + q * 8] = *(const uint4*)(Fg + (size_t)n * 384 + q * 8);
  }
  if (tid < 16) cnt[tid] = 0;
  __syncthreads();

  for (int t = tid; t < 384; t += 512) {
    const int m = t / 24, ch = t - m * 24;
    const int pw = m >> 2, ph = m & 3;
    float sum = 0.f;
    for (int dw = 0; dw < 8; dw++) {
      const int base = (pw * 8 + dw) * 32 + ph * 8;
      for (int dh = 0; dh < 8; dh++) sum += u2f(S[(base + dh) * 24 + ch]);
    }
    cn[m][ch] = sum * (1.f / 64.f);
  }
  __syncthreads();
  if (tid < 16) {
    float s = 0.f;
    for (int ch = 0; ch < 24; ch++) { const float v = cn[tid][ch]; s += v * v; }
    rcn[tid] = 1.f / fmaxf(sqrtf(s), 1e-12f);
  }
  __syncthreads();

  const int na = tid, nb = tid + 512;
  float besta = -3.4e38f, bestb = -3.4e38f;
  int bma = 0, bmb = 0;
  {
    float xa[24], xb[24];
    const uint4* ra = (const uint4*)&S[na * 24];
    const uint4* rb = (const uint4*)&S[nb * 24];
#pragma unroll
    for (int q = 0; q < 3; q++) {
      unpack8(ra[q], &xa[q * 8]);
      unpack8(rb[q], &xb[q * 8]);
    }
    float ssa = 0.f, ssb = 0.f;
#pragma unroll
    for (int ch = 0; ch < 24; ch++) {
      ssa = fmaf(xa[ch], xa[ch], ssa);
      ssb = fmaf(xb[ch], xb[ch], ssb);
    }
    const float rna = 1.f / fmaxf(sqrtf(ssa), 1e-12f);
    const float rnb = 1.f / fmaxf(sqrtf(ssb), 1e-12f);
    for (int m = 0; m < 16; m++) {
      float da = 0.f, db = 0.f;
#pragma unroll
      for (int k = 0; k < 12; k++) {
        const float2 c = *(const float2*)&cn[m][2 * k];
        da = fmaf(c.x, xa[2 * k], da); da = fmaf(c.y, xa[2 * k + 1], da);
        db = fmaf(c.x, xb[2 * k], db); db = fmaf(c.y, xb[2 * k + 1], db);
      }
      const float rc = rcn[m];
      da *= rna * rc;
      db *= rnb * rc;
      const float dda = sqrtf(fmaxf(2.f - 2.f * da, 1e-12f));
      const float ddb = sqrtf(fmaxf(2.f - 2.f * db, 1e-12f));
      const float za = beta + alpha * expf(-dda);
      const float zb = beta + alpha * expf(-ddb);
      const float sa = (za >= 0.f) ? za : 0.2f * za;
      const float sb = (zb >= 0.f) ? zb : 0.2f * zb;
      if (sa > besta) { besta = sa; bma = m; }
      if (sb > bestb) { bestb = sb; bmb = m; }
    }
    atomicAdd(&cnt[bma], 1);
    atomicAdd(&cnt[bmb], 1);
  }
  __syncthreads();

  for (int c = tid; c < 3072; c += 512) {
    const int n = c / 3, q = c - n * 3;
    *(uint4*)&S[n * 24 + q * 8] = *(const uint4*)(Vg + (size_t)n * 384 + q * 8);
  }
  if (tid < 384) outc[tid / 24][tid - (tid / 24) * 24] = 0.f;
  __syncthreads();

  for (int t = tid; t < 384; t += 512) {
    const int m = t / 24, ch = t - m * 24;
    const int pw = m >> 2, ph = m & 3;
    float sum = 0.f;
    for (int dw = 0; dw < 8; dw++) {
      const int base = (pw * 8 + dw) * 32 + ph * 8;
      for (int dh = 0; dh < 8; dh++) sum += u2f(S[(base + dh) * 24 + ch]);
    }
    vcen[m][ch] = sum * (1.f / 64.f);
  }

  {
    float va[24], vb[24];
    const uint4* ra = (const uint4*)&S[na * 24];
    const uint4* rb = (const uint4*)&S[nb * 24];
#pragma unroll
    for (int q = 0; q < 3; q++) {
      unpack8(ra[q], &va[q * 8]);
      unpack8(rb[q], &vb[q * 8]);
    }
#pragma unroll
    for (int ch = 0; ch < 24; ch++) {
      atomicAdd(&outc[bma][ch], besta * va[ch]);
      atomicAdd(&outc[bmb][ch], bestb * vb[ch]);
    }
  }
  __syncthreads();

  for (int t = tid; t < 384; t += 512) {
    const int m = t / 24, ch = t - m * 24;
    outc[m][ch] = (outc[m][ch] + vcen[m][ch]) / ((float)cnt[m] + 1.f);
  }
  __syncthreads();

#pragma unroll
  for (int pass = 0; pass < 2; pass++) {
    const int n = pass ? nb : na;
    const int m = pass ? bmb : bma;
    const float s = pass ? bestb : besta;
    unsigned w[12];
#pragma unroll
    for (int k = 0; k < 12; k++) {
      w[k] = (unsigned)f2u(s * outc[m][2 * k]) |
             ((unsigned)f2u(s * outc[m][2 * k + 1]) << 16);
    }
    uint4* dst = (uint4*)(Fg + (size_t)n * 384);
    dst[0] = make_uint4(w[0], w[1], w[2], w[3]);
    dst[1] = make_uint4(w[4], w[5], w[6], w[7]);
    dst[2] = make_uint4(w[8], w[9], w[10], w[11]);
  }
}

// ---------------------------------------------------------------------------
// Workspace layout (floor 48.1 MB; G beyond that, adaptive):
//   flag @0 | fv_w @256 | proj_w @590080 | fc1_w @884992 | fc2_w @5603584
//   fvb @10322176 | projb @10322944 | fc1b @10324480 | fc2b @10330624
//   Y1 bf16 16384x768 @10332416 | FV bf16 16384x384 @35498240 | G @48081152
// ---------------------------------------------------------------------------
extern "C" void kernel_launch(void* const* d_in, const int* in_sizes, int n_in,
                              void* d_out, int out_size, void* d_ws, size_t ws_size,
                              hipStream_t stream) {
  const void* x      = d_in[0];
  const void* ln1_w  = d_in[1];
  const void* ln1_b  = d_in[2];
  const void* f_w    = d_in[3];
  const void* f_b    = d_in[4];
  const void* v_w    = d_in[5];
  const void* v_b    = d_in[6];
  const void* proj_w = d_in[7];
  const void* proj_b = d_in[8];
  const void* alpha  = d_in[9];
  const void* beta   = d_in[10];
  const void* ln2_w  = d_in[11];
  const void* ln2_b  = d_in[12];
  const void* fc1_w  = d_in[13];
  const void* fc1_b  = d_in[14];
  const void* fc2_w  = d_in[15];
  const void* fc2_b  = d_in[16];

  char* ws = (char*)d_ws;
  int* flag  = (int*)(ws + 0);
  u16* fvw   = (u16*)(ws + 256);
  u16* prw   = (u16*)(ws + 590080);
  u16* f1w   = (u16*)(ws + 884992);
  u16* f2w   = (u16*)(ws + 5603584);
  u16* fvb   = (u16*)(ws + 10322176);
  u16* prb   = (u16*)(ws + 10322944);
  u16* f1b   = (u16*)(ws + 10324480);
  u16* f2b_  = (u16*)(ws + 10330624);
  u16* Y1    = (u16*)(ws + 10332416);
  u16* FV    = (u16*)(ws + 35498240);
  u16* Gext  = (u16*)(ws + 48081152);

  // fc1/fc2 chunk rows (multiple of 256), pure function of ws_size.
  const long extra = (long)ws_size - 48081152L;
  u16* G; long crows;
  if (extra >= (long)NTOK * HID_ * 2) { G = Gext; crows = NTOK; }
  else if (extra >= 256L * HID_ * 2) { G = Gext; crows = (extra / (HID_ * 2)) / 256 * 256; }
  else { G = FV; crows = 2048; }  // FV dead after proj; 2048*3072*2 = 12.58 MB fits

  detect_kernel<<<1, 64, 0, stream>>>((const unsigned*)x, flag);

  CvtArgs ca;
  ca.j[0] = {f_w,    fvw,            147456 / 4};
  ca.j[1] = {v_w,    fvw + 147456,   147456 / 4};
  ca.j[2] = {proj_w, prw,            147456 / 4};
  ca.j[3] = {fc1_w,  f1w,            2359296 / 4};
  ca.j[4] = {fc2_w,  f2w,            2359296 / 4};
  ca.j[5] = {f_b,    fvb,            192 / 4};
  ca.j[6] = {v_b,    fvb + 192,      192 / 4};
  ca.j[7] = {proj_b, prb,            768 / 4};
  ca.j[8] = {fc1_b,  f1b,            3072 / 4};
  ca.j[9] = {fc2_b,  f2b_,           768 / 4};
  cvt_kernel<<<dim3(2304, 10), 256, 0, stream>>>(ca, flag);

  // ln1(x) -> Y1 (bf16)
  ln_kernel<<<NTOK, 256, 0, stream>>>(x, ln1_w, ln1_b, Y1, flag);
  // FV = Y1 * [f_w; v_w]^T + [f_b; v_b]   (M=16384, N=384, K=768) -- gemmS
  mfma_gemmS<0><<<dim3(128, 3), 256, 0, stream>>>(
      Y1, D_, fvw, D_, fvb, nullptr, FV, 384, D_, 0, flag);
  cluster_kernel<<<128, 512, 0, stream>>>(FV, alpha, beta, flag);
  // h = CL * proj_w^T + proj_b + x -> d_out (flag dtype) -- gemmS
  mfma_gemmS<2><<<dim3(128, 6), 256, 0, stream>>>(
      FV, 384, prw, INNER_, prb, x, d_out, D_, INNER_, 0, flag);
  // ln2(h) -> Y1 (bf16)
  ln_kernel<<<NTOK, 256, 0, stream>>>(d_out, ln2_w, ln2_b, Y1, flag);
  // fc1 -> G (gelu), fc2 + h residual -> d_out in place, chunked (128x256)
  for (long t0 = 0; t0 < NTOK; t0 += crows) {
    const long ct = (t0 + crows <= NTOK) ? crows : (NTOK - t0);
    const int gm1 = (int)(ct / 128), gn1 = HID_ / 256;
    const int gm2 = (int)(ct / 128), gn2 = D_ / 256;
    mfma_gemmP<1><<<dim3(gm1 * gn1), 512, 0, stream>>>(
        Y1 + t0 * D_, D_, f1w, D_, f1b, nullptr, G, HID_, D_, 0, gm1, gn1, flag);
    mfma_gemmP<2><<<dim3(gm2 * gn2), 512, 0, stream>>>(
        G, HID_, f2w, HID_, f2b_, d_out, d_out, D_, HID_, (int)t0, gm2, gn2, flag);
  }
}